// Round 8
// baseline (528.142 us; speedup 1.0000x reference)
//
#include <hip/hip_runtime.h>
#include <cmath>

#define N_NODES   100000
#define N_EDGES   3200000
#define D_FEAT    512
#define HIDDEN    16
#define N_CLASSES 7

#define NCHUNK 250                   // pass-1 blocks of 1024 thr; 250*12800 = 3.2M exactly
#define CHUNK  12800
#define NBKT   1563                  // buckets of 64 nodes (dst>>6)
#define BCAP   4096                  // LDS edge-cache capacity in k_bucket (avg 2048)

typedef __attribute__((ext_vector_type(4))) float  f32x4;
typedef __attribute__((ext_vector_type(8))) short  bf16x8;

__device__ __forceinline__ short f2bf(float f) {
    union { float f; unsigned u; } v; v.f = f;
    unsigned r = v.u + 0x7fffu + ((v.u >> 16) & 1u);   // RNE
    return (short)(r >> 16);
}
__device__ __forceinline__ float bf2f(unsigned short s) {
    union { unsigned u; float f; } v; v.u = ((unsigned)s) << 16;
    return v.f;
}

// ---------------- pass 1a: per-chunk bucket histogram (LDS atomics only) ---
__global__ __launch_bounds__(1024) void k_hist1(const int* __restrict__ dst,
                                                unsigned* __restrict__ hist) {
    __shared__ unsigned h[NBKT];
    int t = threadIdx.x, b = blockIdx.x;
    for (int i = t; i < NBKT; i += 1024) h[i] = 0u;
    __syncthreads();
    int base = b * CHUNK;
    #pragma unroll 2
    for (int k = 0; k < 13; ++k) {
        int idx = k * 1024 + t;
        if (idx < CHUNK) atomicAdd(&h[((unsigned)dst[base + idx]) >> 6], 1u);
    }
    __syncthreads();
    for (int i = t; i < NBKT; i += 1024)
        hist[(size_t)i * NCHUNK + b] = h[i];   // bin-major
}

// -------- scan A: per-bin exclusive scan of its NCHUNK entries (in place) --
__global__ __launch_bounds__(256) void k_scan_a(unsigned* __restrict__ hist,
                                                unsigned* __restrict__ bin_total) {
    __shared__ unsigned t0[256];
    int t = threadIdx.x, b = blockIdx.x;
    unsigned v = (t < NCHUNK) ? hist[(size_t)b * NCHUNK + t] : 0u;
    t0[t] = v; __syncthreads();
    #pragma unroll
    for (int off = 1; off < 256; off <<= 1) {
        unsigned add = (t >= off) ? t0[t - off] : 0u;
        __syncthreads();
        t0[t] += add;
        __syncthreads();
    }
    if (t < NCHUNK) hist[(size_t)b * NCHUNK + t] = t0[t] - v;   // excl within bin
    if (t == 255) bin_total[b] = t0[t];
}

// -------- scan B: exclusive scan of 1563 bin totals (single block) ---------
__global__ __launch_bounds__(256) void k_scan_b(const unsigned* __restrict__ bin_total,
                                                unsigned* __restrict__ bin_base) {
    __shared__ unsigned t0[256];
    int t = threadIdx.x;
    unsigned running = 0u;
    for (int c0 = 0; c0 < NBKT; c0 += 256) {
        int i = c0 + t;
        unsigned v = (i < NBKT) ? bin_total[i] : 0u;
        t0[t] = v; __syncthreads();
        #pragma unroll
        for (int off = 1; off < 256; off <<= 1) {
            unsigned add = (t >= off) ? t0[t - off] : 0u;
            __syncthreads();
            t0[t] += add;
            __syncthreads();
        }
        if (i < NBKT) bin_base[i] = running + t0[t] - v;
        unsigned chunk_sum = t0[255];
        __syncthreads();
        running += chunk_sum;
    }
    if (t == 0) bin_base[NBKT] = running;   // == N_EDGES
}

// ---------------- pass 1b: scatter packed edges into bucket-major order ----
// packed word = (dst & 63) << 24 | src    (src < 100000 < 2^24)
__global__ __launch_bounds__(1024) void k_scatter1(const int* __restrict__ src,
                                                   const int* __restrict__ dst,
                                                   const unsigned* __restrict__ hist,
                                                   const unsigned* __restrict__ bin_base,
                                                   unsigned* __restrict__ packed) {
    __shared__ unsigned cur[NBKT];
    int t = threadIdx.x, b = blockIdx.x;
    for (int i = t; i < NBKT; i += 1024)
        cur[i] = hist[(size_t)i * NCHUNK + b] + bin_base[i];
    __syncthreads();
    int base = b * CHUNK;
    #pragma unroll 2
    for (int k = 0; k < 13; ++k) {
        int idx = k * 1024 + t;
        if (idx < CHUNK) {
            int e = base + idx;
            unsigned d = (unsigned)dst[e];
            unsigned pos = atomicAdd(&cur[d >> 6], 1u);   // LDS atomic
            packed[pos] = ((d & 63u) << 24) | (unsigned)src[e];
        }
    }
}

// -------- pass 2: per-bucket exact-dst sort -> deg, row_start, dinv, csr ---
// Bucket edge slice cached in LDS (avg 2048, cap 4096; global fallback).
__global__ __launch_bounds__(256) void k_bucket(const unsigned* __restrict__ packed,
                                                const unsigned* __restrict__ bin_base,
                                                unsigned* __restrict__ deg,
                                                unsigned* __restrict__ row_start,
                                                float* __restrict__ dinv,
                                                int* __restrict__ csr_src) {
    __shared__ unsigned pbuf[BCAP];
    __shared__ unsigned hh[4][64], sc[64], cur[64];
    int t = threadIdx.x, b = blockIdx.x;
    int w = t >> 6, l = t & 63;
    unsigned rs = bin_base[b];
    unsigned re = bin_base[b + 1];
    unsigned n  = re - rs;
    bool fits = (n <= BCAP);
    if (fits)
        for (unsigned i = t; i < n; i += 256) pbuf[i] = packed[rs + i];
    hh[w][l] = 0u;
    __syncthreads();
    for (unsigned i = t; i < n; i += 256) {
        unsigned p = fits ? pbuf[i] : packed[rs + i];
        atomicAdd(&hh[w][p >> 24], 1u);    // per-wave sub-hist
    }
    __syncthreads();
    unsigned total = 0u;
    if (t < 64) {
        total = hh[0][t] + hh[1][t] + hh[2][t] + hh[3][t];
        sc[t] = total;
    }
    __syncthreads();
    #pragma unroll
    for (int off = 1; off < 64; off <<= 1) {
        unsigned add = (t >= off && t < 64) ? sc[t - off] : 0u;
        __syncthreads();
        if (t < 64) sc[t] += add;
        __syncthreads();
    }
    if (t < 64) {
        unsigned excl = sc[t] - total;
        int node = b * 64 + t;
        if (node < N_NODES) {
            deg[node]       = total;
            row_start[node] = rs + excl;
            dinv[node]      = rsqrtf((float)(total + 1u));
        }
        cur[t] = rs + excl;
    }
    __syncthreads();
    for (unsigned i = t; i < n; i += 256) {
        unsigned p = fits ? pbuf[i] : packed[rs + i];
        unsigned pos = atomicAdd(&cur[p >> 24], 1u);     // LDS atomic
        csr_src[pos] = (int)(p & 0xFFFFFFu);
    }
}

// ------- GEMM1: h1p = bf16( dinv .* (x@W1) )  (bf16 MFMA, fp32 acc) --------
__global__ __launch_bounds__(256) void k_gemm1(const float* __restrict__ x,
                                               const float* __restrict__ w1,
                                               const float* __restrict__ dinv,
                                               unsigned short* __restrict__ h1p) {
    __shared__ __align__(16) short w1t[16][520];
    int tid = threadIdx.x;
    for (int idx = tid; idx < D_FEAT * HIDDEN; idx += 256) {
        int k = idx >> 4, n = idx & 15;
        w1t[n][k] = f2bf(w1[idx]);
    }
    __syncthreads();

    int lane = tid & 63, wid = tid >> 6;
    int m  = lane & 15;
    int kg = lane >> 4;

    bf16x8 bfrag[16];
    #pragma unroll
    for (int ks = 0; ks < 16; ++ks)
        bfrag[ks] = *(const bf16x8*)&w1t[m][ks * 32 + kg * 8];

    int tile = blockIdx.x * 4 + wid;
    if (tile >= (N_NODES / 16)) return;

    const f32x4* xr = (const f32x4*)(x + (size_t)(tile * 16 + m) * D_FEAT);
    f32x4 acc = {0.f, 0.f, 0.f, 0.f};
    #pragma unroll
    for (int ks = 0; ks < 16; ++ks) {
        f32x4 x0 = xr[ks * 8 + kg * 2];
        f32x4 x1 = xr[ks * 8 + kg * 2 + 1];
        bf16x8 a;
        a[0] = f2bf(x0[0]); a[1] = f2bf(x0[1]); a[2] = f2bf(x0[2]); a[3] = f2bf(x0[3]);
        a[4] = f2bf(x1[0]); a[5] = f2bf(x1[1]); a[6] = f2bf(x1[2]); a[7] = f2bf(x1[3]);
        acc = __builtin_amdgcn_mfma_f32_16x16x32_bf16(a, bfrag[ks], acc, 0, 0, 0);
    }
    // C layout: col = lane&15, row = (lane>>4)*4 + reg  [m89-verified]
    size_t base = (size_t)tile * 256;
    #pragma unroll
    for (int r = 0; r < 4; ++r) {
        int rr = kg * 4 + r;
        h1p[base + rr * 16 + m] = (unsigned short)f2bf(dinv[tile * 16 + rr] * acc[r]);
    }
}

// ------- gather layer 1 + ReLU + W2 transform fused ------------------------
// One wave per node; lane = sl*16 + j (j = feature). Uniform predicated loop,
// 4 independent loads in flight. Epilogue: m1 -> relu -> @W2 -> bf16 h2p row.
__global__ __launch_bounds__(256) void k_gather1(const int* __restrict__ csr_src,
                                                 const unsigned* __restrict__ row_start,
                                                 const unsigned* __restrict__ deg,
                                                 const float* __restrict__ dinv,
                                                 const unsigned short* __restrict__ h1p,
                                                 const float* __restrict__ w2,
                                                 const float* __restrict__ b1,
                                                 unsigned short* __restrict__ h2p) {
    int tid  = threadIdx.x;
    int lane = tid & 63;
    int node = blockIdx.x * 4 + (tid >> 6);   // grid 25000 -> exactly 100000
    int j  = lane & 15;
    int sl = lane >> 4;          // 0..3

    float b1j = b1[j];
    float w2j[N_CLASSES];
    #pragma unroll
    for (int c = 0; c < N_CLASSES; ++c) w2j[c] = w2[j * N_CLASSES + c];

    unsigned start = row_start[node];
    unsigned end   = start + deg[node];

    float acc = (sl == 0) ? bf2f(h1p[(size_t)node * 16 + j]) : 0.f;   // self
    for (unsigned e0 = start; e0 < end; e0 += 16) {
        unsigned i0 = e0 + (unsigned)sl, i1 = i0 + 4, i2 = i0 + 8, i3 = i0 + 12;
        int s0 = (i0 < end) ? csr_src[i0] : 0;
        int s1 = (i1 < end) ? csr_src[i1] : 0;
        int s2 = (i2 < end) ? csr_src[i2] : 0;
        int s3 = (i3 < end) ? csr_src[i3] : 0;
        float v0 = (i0 < end) ? bf2f(h1p[(size_t)s0 * 16 + j]) : 0.f;
        float v1 = (i1 < end) ? bf2f(h1p[(size_t)s1 * 16 + j]) : 0.f;
        float v2 = (i2 < end) ? bf2f(h1p[(size_t)s2 * 16 + j]) : 0.f;
        float v3 = (i3 < end) ? bf2f(h1p[(size_t)s3 * 16 + j]) : 0.f;
        acc += v0; acc += v1; acc += v2; acc += v3;
    }
    acc += __shfl_down(acc, 32);
    acc += __shfl_down(acc, 16);
    // lanes 0..15 hold the 16 feature sums of this node
    float di = dinv[node];
    float h = fmaxf(di * acc + b1j, 0.f);
    float s[N_CLASSES];
    #pragma unroll
    for (int c = 0; c < N_CLASSES; ++c) s[c] = h * w2j[c];
    #pragma unroll
    for (int mk = 1; mk < 16; mk <<= 1) {
        #pragma unroll
        for (int c = 0; c < N_CLASSES; ++c) s[c] += __shfl_xor(s[c], mk, 16);
    }
    if (lane == 0) {
        unsigned u0 = (unsigned)(unsigned short)f2bf(di * s[0]) |
                      ((unsigned)(unsigned short)f2bf(di * s[1]) << 16);
        unsigned u1 = (unsigned)(unsigned short)f2bf(di * s[2]) |
                      ((unsigned)(unsigned short)f2bf(di * s[3]) << 16);
        unsigned u2 = (unsigned)(unsigned short)f2bf(di * s[4]) |
                      ((unsigned)(unsigned short)f2bf(di * s[5]) << 16);
        unsigned u3 = (unsigned)(unsigned short)f2bf(di * s[6]);   // hi = bf16(0)
        uint4 pk; pk.x = u0; pk.y = u1; pk.z = u2; pk.w = u3;
        *(uint4*)(h2p + (size_t)node * 8) = pk;
    }
}

// ------- gather layer 2 + bias + log_softmax fused -------------------------
// One wave per node; lane = sl*8 + j (j = class). Uniform predicated loop.
__global__ __launch_bounds__(256) void k_gather2(const int* __restrict__ csr_src,
                                                 const unsigned* __restrict__ row_start,
                                                 const unsigned* __restrict__ deg,
                                                 const float* __restrict__ dinv,
                                                 const unsigned short* __restrict__ h2p,
                                                 const float* __restrict__ b2,
                                                 float* __restrict__ out) {
    int tid  = threadIdx.x;
    int lane = tid & 63;
    int node = blockIdx.x * 4 + (tid >> 6);
    int j  = lane & 7;
    int sl = lane >> 3;          // 0..7

    unsigned start = row_start[node];
    unsigned end   = start + deg[node];

    float acc = (sl == 0) ? bf2f(h2p[(size_t)node * 8 + j]) : 0.f;    // self
    for (unsigned e0 = start; e0 < end; e0 += 32) {
        unsigned i0 = e0 + (unsigned)sl, i1 = i0 + 8, i2 = i0 + 16, i3 = i0 + 24;
        int s0 = (i0 < end) ? csr_src[i0] : 0;
        int s1 = (i1 < end) ? csr_src[i1] : 0;
        int s2 = (i2 < end) ? csr_src[i2] : 0;
        int s3 = (i3 < end) ? csr_src[i3] : 0;
        float v0 = (i0 < end) ? bf2f(h2p[(size_t)s0 * 8 + j]) : 0.f;
        float v1 = (i1 < end) ? bf2f(h2p[(size_t)s1 * 8 + j]) : 0.f;
        float v2 = (i2 < end) ? bf2f(h2p[(size_t)s2 * 8 + j]) : 0.f;
        float v3 = (i3 < end) ? bf2f(h2p[(size_t)s3 * 8 + j]) : 0.f;
        acc += v0; acc += v1; acc += v2; acc += v3;
    }
    acc += __shfl_down(acc, 32);
    acc += __shfl_down(acc, 16);
    acc += __shfl_down(acc, 8);
    float di = dinv[node];
    float logit = (j < N_CLASSES) ? di * acc + b2[j] : -1e30f;
    float mx = logit;
    #pragma unroll
    for (int mk = 1; mk < 8; mk <<= 1) mx = fmaxf(mx, __shfl_xor(mx, mk, 8));
    float ex = (j < N_CLASSES) ? __expf(logit - mx) : 0.f;
    float sum = ex;
    #pragma unroll
    for (int mk = 1; mk < 8; mk <<= 1) sum += __shfl_xor(sum, mk, 8);
    if (sl == 0 && j < N_CLASSES)
        out[(size_t)node * N_CLASSES + j] = logit - mx - __logf(sum);
}

extern "C" void kernel_launch(void* const* d_in, const int* in_sizes, int n_in,
                              void* d_out, int out_size, void* d_ws, size_t ws_size,
                              hipStream_t stream) {
    const float* x  = (const float*)d_in[0];
    const int*   ei = (const int*)d_in[1];
    const float* w1 = (const float*)d_in[2];
    const float* b1 = (const float*)d_in[3];
    const float* w2 = (const float*)d_in[4];
    const float* b2 = (const float*)d_in[5];
    float* out = (float*)d_out;

    const int* src = ei;
    const int* dst = ei + N_EDGES;

    // workspace carve (u32 units), ~33 MB
    unsigned* w32        = (unsigned*)d_ws;
    float*    dinv       = (float*)(w32 + 0);               // 102,400
    unsigned short* h1p  = (unsigned short*)(w32 + 102400); // 1.6M ushort = 800,000 u32
    unsigned short* h2p  = (unsigned short*)(w32 + 902400); // 800k ushort = 400,000 u32
    unsigned* deg        = w32 + 1302400;                   // 102,400
    unsigned* row_start  = w32 + 1404800;                   // 102,400
    unsigned* hist       = w32 + 1507200;                   // 390,784
    unsigned* bin_total  = w32 + 1897984;                   // 1,568
    unsigned* bin_base   = w32 + 1899552;                   // 1,568
    unsigned* packed     = w32 + 1901120;                   // 3,200,000
    int*      csr_src    = (int*)(w32 + 5101120);           // 3,200,000

    const int GB = (N_NODES / 16 + 3) / 4;                  // 1563 gemm blocks

    k_hist1   <<<NCHUNK, 1024, 0, stream>>>(dst, hist);
    k_scan_a  <<<NBKT,   256,  0, stream>>>(hist, bin_total);
    k_scan_b  <<<1,      256,  0, stream>>>(bin_total, bin_base);
    k_scatter1<<<NCHUNK, 1024, 0, stream>>>(src, dst, hist, bin_base, packed);
    k_bucket  <<<NBKT,   256,  0, stream>>>(packed, bin_base, deg, row_start, dinv, csr_src);
    k_gemm1   <<<GB,     256,  0, stream>>>(x, w1, dinv, h1p);
    k_gather1 <<<25000,  256,  0, stream>>>(csr_src, row_start, deg, dinv, h1p, w2, b1, h2p);
    k_gather2 <<<25000,  256,  0, stream>>>(csr_src, row_start, deg, dinv, h2p, b2, out);
}